// Round 7
// baseline (233.465 us; speedup 1.0000x reference)
//
#include <hip/hip_runtime.h>
#include <hip/hip_bf16.h>

#define DEVI __device__ __forceinline__

typedef __attribute__((ext_vector_type(8))) _Float16 f16x8;
typedef __attribute__((ext_vector_type(4))) float f32x4;
typedef __attribute__((ext_vector_type(4))) unsigned short us4;

DEVI unsigned short f2h(float f) {
  union { _Float16 h; unsigned short u; } v;
  v.h = (_Float16)f;
  return v.u;
}

// ---------------- elementwise convert x -> fp16 ----------------
__global__ void __launch_bounds__(256) k_convert_f16(
    const float* __restrict__ x, unsigned short* __restrict__ o, int n4) {
  int i = blockIdx.x * 256 + threadIdx.x;
  if (i >= n4) return;
  float4 v = reinterpret_cast<const float4*>(x)[i];
  us4 h;
  h[0] = f2h(v.x); h[1] = f2h(v.y); h[2] = f2h(v.z); h[3] = f2h(v.w);
  reinterpret_cast<us4*>(o)[i] = h;
}

// ------------- merged transpose: 4 weights [K][N] -> WT[N][K] fp16 -------------
__global__ void __launch_bounds__(256) k_transpose4(
    const float* __restrict__ W0, const float* __restrict__ W1,
    const float* __restrict__ W2, const float* __restrict__ W3,
    unsigned short* __restrict__ T0, unsigned short* __restrict__ T1,
    unsigned short* __restrict__ T2, unsigned short* __restrict__ T3, int n) {
  const int zz = blockIdx.z;
  const float* W = (zz == 0) ? W0 : (zz == 1) ? W1 : (zz == 2) ? W2 : W3;
  unsigned short* T = (zz == 0) ? T0 : (zz == 1) ? T1 : (zz == 2) ? T2 : T3;
  __shared__ float t[32][33];
  int tx = threadIdx.x & 31, ty = threadIdx.x >> 5;
  int n0 = blockIdx.x * 32, k0 = blockIdx.y * 32;
#pragma unroll
  for (int r = 0; r < 4; ++r)
    t[ty + r * 8][tx] = W[(size_t)(k0 + ty + r * 8) * n + n0 + tx];
  __syncthreads();
#pragma unroll
  for (int r = 0; r < 4; ++r) {
    int nn = n0 + ty + r * 8;
    T[(size_t)nn * n + k0 + tx] = f2h(t[tx][ty + r * 8]);
  }
}

// ---------------- GEMM: C[M][N] = A[M][K] * B_T[N][K]  (fp16, K-contiguous)
// Round-4 proven config: 128x128 tile, BK=64, 256 thr, 4 blocks/CU.
// XOR-swizzled LDS: slot (r,s) holds global chunk (r, s^(r&7)); staged with
// inverse-swizzled global source + linear LDS dest (global_load_lds x16B);
// read slot = (kk*4+lr) ^ (row&7)  -> conflict-free ds_read_b128.
DEVI void gload16(const unsigned short* gp, unsigned short* lp) {
  __builtin_amdgcn_global_load_lds(
      (const __attribute__((address_space(1))) unsigned int*)gp,
      (__attribute__((address_space(3))) unsigned int*)lp, 16, 0, 0);
}

DEVI void stage_tile64(unsigned short* lbase, const unsigned short* g, int ldg,
                       int wid, int lane) {
#pragma unroll
  for (int it = 0; it < 4; ++it) {
    int chunk = it * 256 + wid * 64 + lane;
    int r = chunk >> 3, s = chunk & 7;
    int c = (s ^ (r & 7)) * 8;
    gload16(g + (size_t)r * ldg + c, lbase + (it * 256 + wid * 64) * 8);
  }
}

DEVI f16x8 frag(const unsigned short* base, int row, int kk, int lr) {
  int slot = (kk * 4 + lr) ^ (row & 7);
  return *reinterpret_cast<const f16x8*>(base + row * 64 + slot * 8);
}

// EPI: 0 = fused QKV epilogue: bias; q,k fp16 row-major; v fp16 transposed v_t
//      2 = write fp32 (scores, z-strided)
//      3 = write fp16 (attn = P*V, z-strided)
//      4 = bias + residual + write fp32 (out proj)
template <int EPI>
__global__ void __launch_bounds__(256, 4) k_gemm(
    const unsigned short* __restrict__ A, const unsigned short* __restrict__ B,
    int K, int ldA, int ldB,
    size_t azs, size_t bzs, size_t czs,
    const float* __restrict__ b0, const float* __restrict__ b1,
    const float* __restrict__ b2, const float* __restrict__ resid,
    float* __restrict__ outF, unsigned short* __restrict__ o0,
    unsigned short* __restrict__ o1, unsigned short* __restrict__ o2, int ldc) {
  __shared__ unsigned short lds[2 * 8192];
  unsigned short* Alds = lds;
  unsigned short* Blds = lds + 8192;

  // bijective chunked XCD swizzle (all launch grids have nwg % 8 == 0)
  const int gx = gridDim.x, gy = gridDim.y;
  const int nwg = gx * gy * gridDim.z;
  const int l = (blockIdx.z * gy + blockIdx.y) * gx + blockIdx.x;
  const int nl = (l & 7) * (nwg >> 3) + (l >> 3);
  const int bx = nl % gx;
  const int rem = nl / gx;
  const int by = rem % gy;
  const int z = rem / gy;

  const int tid = threadIdx.x, lane = tid & 63, wid = tid >> 6;
  const int wr = (wid >> 1) * 64, wc = (wid & 1) * 64;
  const int lc = lane & 15, lr = lane >> 4;
  const size_t row0 = (size_t)bx * 128, col0 = (size_t)by * 128;

  const unsigned short* Ag = A + (size_t)z * azs + row0 * ldA;
  const unsigned short* Bg = B + (size_t)z * bzs + col0 * ldB;

  f32x4 acc[4][4] = {};

  for (int k0 = 0; k0 < K; k0 += 64) {
    stage_tile64(Alds, Ag + k0, ldA, wid, lane);
    stage_tile64(Blds, Bg + k0, ldB, wid, lane);
    __syncthreads();
#pragma unroll
    for (int kk = 0; kk < 2; ++kk) {
      f16x8 af[4], bf[4];
#pragma unroll
      for (int i = 0; i < 4; ++i) {
        af[i] = frag(Alds, wr + i * 16 + lc, kk, lr);
        bf[i] = frag(Blds, wc + i * 16 + lc, kk, lr);
      }
#pragma unroll
      for (int mi = 0; mi < 4; ++mi)
#pragma unroll
        for (int ni = 0; ni < 4; ++ni)
          acc[mi][ni] = __builtin_amdgcn_mfma_f32_16x16x32_f16(af[mi], bf[ni], acc[mi][ni], 0, 0, 0);
    }
    __syncthreads();
  }

#pragma unroll
  for (int mi = 0; mi < 4; ++mi) {
#pragma unroll
    for (int ni = 0; ni < 4; ++ni) {
      const int r0 = (int)row0 + wr + mi * 16 + lr * 4;
      const int c = (int)col0 + wc + ni * 16 + lc;
      f32x4 a = acc[mi][ni];
      if (EPI == 0) {
        const int sub = c >> 10;  // 128-tile never spans q/k/v boundary
        const int cc = c & 1023;
        if (sub == 0) {
          float bb = b0[cc];
#pragma unroll
          for (int r = 0; r < 4; ++r)
            o0[(size_t)(r0 + r) * 1024 + cc] = f2h(a[r] + bb);
        } else if (sub == 1) {
          float bb = b1[cc];
#pragma unroll
          for (int r = 0; r < 4; ++r)
            o1[(size_t)(r0 + r) * 1024 + cc] = f2h(a[r] + bb);
        } else {
          float bb = b2[cc];
          us4 pk;
#pragma unroll
          for (int r = 0; r < 4; ++r) pk[r] = f2h(a[r] + bb);
          // v_t[b][d=cc][s]: 4 consecutive s at fixed d
          *reinterpret_cast<us4*>(o2 + ((size_t)(r0 >> 11) * 1024 + cc) * 2048 + (r0 & 2047)) = pk;
        }
      } else if (EPI == 2) {
#pragma unroll
        for (int r = 0; r < 4; ++r)
          outF[(size_t)z * czs + (size_t)(r0 + r) * ldc + c] = a[r];
      } else if (EPI == 3) {
#pragma unroll
        for (int r = 0; r < 4; ++r)
          o0[(size_t)z * czs + (size_t)(r0 + r) * ldc + c] = f2h(a[r]);
      } else {
        float bb = b0[c];
#pragma unroll
        for (int r = 0; r < 4; ++r) {
          size_t idx = (size_t)(r0 + r) * ldc + c;
          outF[idx] = a[r] + bb + resid[idx];
        }
      }
    }
  }
}

// ---------------- row softmax: scores fp32 [8192][2048] -> P fp16 [8192][2048]
__global__ void __launch_bounds__(256) k_softmax(
    const float* __restrict__ S, unsigned short* __restrict__ P) {
  __shared__ float red[4];
  const int row = blockIdx.x, tid = threadIdx.x;
  const int lane = tid & 63, wid = tid >> 6;
  const float* src = S + (size_t)row * 2048;
  float4 v0 = *reinterpret_cast<const float4*>(src + tid * 8);
  float4 v1 = *reinterpret_cast<const float4*>(src + tid * 8 + 4);
  float vv[8] = {v0.x, v0.y, v0.z, v0.w, v1.x, v1.y, v1.z, v1.w};
  float m = vv[0];
#pragma unroll
  for (int j = 1; j < 8; ++j) m = fmaxf(m, vv[j]);
#pragma unroll
  for (int o = 32; o > 0; o >>= 1) m = fmaxf(m, __shfl_xor(m, o));
  if (lane == 0) red[wid] = m;
  __syncthreads();
  m = fmaxf(fmaxf(red[0], red[1]), fmaxf(red[2], red[3]));
  __syncthreads();
  float e[8];
  float s = 0.f;
#pragma unroll
  for (int j = 0; j < 8; ++j) { e[j] = __expf(vv[j] - m); s += e[j]; }
#pragma unroll
  for (int o = 32; o > 0; o >>= 1) s += __shfl_xor(s, o);
  if (lane == 0) red[wid] = s;
  __syncthreads();
  s = red[0] + red[1] + red[2] + red[3];
  float inv = 1.0f / s;
  us4 p0, p1;
#pragma unroll
  for (int j = 0; j < 4; ++j) p0[j] = f2h(e[j] * inv);
#pragma unroll
  for (int j = 0; j < 4; ++j) p1[j] = f2h(e[j + 4] * inv);
  us4* dst = reinterpret_cast<us4*>(P + (size_t)row * 2048 + tid * 8);
  dst[0] = p0;
  dst[1] = p1;
}

extern "C" void kernel_launch(void* const* d_in, const int* in_sizes, int n_in,
                              void* d_out, int out_size, void* d_ws, size_t ws_size,
                              hipStream_t stream) {
  (void)in_sizes; (void)n_in; (void)out_size; (void)ws_size;
  const float* x  = (const float*)d_in[0];
  const float* Wq = (const float*)d_in[1];
  const float* bq = (const float*)d_in[2];
  const float* Wk = (const float*)d_in[3];
  const float* bk = (const float*)d_in[4];
  const float* Wv = (const float*)d_in[5];
  const float* bv = (const float*)d_in[6];
  const float* Wo = (const float*)d_in[7];
  const float* bo = (const float*)d_in[8];
  float* out = (float*)d_out;

  char* p = (char*)d_ws;
  auto take = [&](size_t bytes) {
    char* r = p;
    p += (bytes + 255) & ~(size_t)255;
    return r;
  };
  const size_t SD = (size_t)4 * 2048 * 1024;  // 8388608 elements
  unsigned short* x_h   = (unsigned short*)take(SD * 2);
  unsigned short* q_h   = (unsigned short*)take(SD * 2);
  unsigned short* k_h   = (unsigned short*)take(SD * 2);
  unsigned short* WqkvT = (unsigned short*)take((size_t)3072 * 1024 * 2);
  unsigned short* WoT   = (unsigned short*)take((size_t)1024 * 1024 * 2);
  unsigned short* v_t   = (unsigned short*)take(SD * 2);   // [B][D][S] fp16
  unsigned short* attn  = (unsigned short*)take(SD * 2);   // [B*S][D] fp16
  const size_t SC_B = (size_t)2048 * 2048;  // score elements per batch
  float* scores       = (float*)take(4 * SC_B * 4);          // fp32 [4][2048][2048]
  unsigned short* Pm  = (unsigned short*)take(4 * SC_B * 2); // fp16 [4][2048][2048]

  dim3 blk(256);
  k_convert_f16<<<dim3(8192), blk, 0, stream>>>(x, x_h, (int)(SD / 4));
  k_transpose4<<<dim3(32, 32, 4), blk, 0, stream>>>(
      Wq, Wk, Wv, Wo,
      WqkvT, WqkvT + (size_t)1024 * 1024, WqkvT + (size_t)2048 * 1024, WoT, 1024);

  // fused QKV projection: [8192 x 1024] x [3072 x 1024]^T
  k_gemm<0><<<dim3(64, 24, 1), blk, 0, stream>>>(
      x_h, WqkvT, 1024, 1024, 1024, 0, 0, 0,
      bq, bk, bv, nullptr, nullptr, q_h, k_h, v_t, 0);

  const size_t QZS = (size_t)2048 * 1024;   // q/k batch stride (elements)
  const size_t VZS = (size_t)1024 * 2048;   // v_t batch stride
  // scores = q . k^T  (fp32 out), all 4 batches
  k_gemm<2><<<dim3(16, 16, 4), blk, 0, stream>>>(
      q_h, k_h, 1024, 1024, 1024, QZS, QZS, SC_B,
      nullptr, nullptr, nullptr, nullptr, scores, nullptr, nullptr, nullptr, 2048);
  // softmax: fp32 scores -> contiguous fp16 P
  k_softmax<<<dim3(8192), blk, 0, stream>>>(scores, Pm);
  // attn = P . V
  k_gemm<3><<<dim3(16, 8, 4), blk, 0, stream>>>(
      Pm, v_t, 2048, 2048, 2048, SC_B, VZS, QZS,
      nullptr, nullptr, nullptr, nullptr, nullptr, attn, nullptr, nullptr, 1024);
  // out = attn . Wo^T + bo + x
  k_gemm<4><<<dim3(64, 8, 1), blk, 0, stream>>>(
      attn, WoT, 1024, 1024, 1024, 0, 0, 0,
      bo, nullptr, nullptr, x, out, nullptr, nullptr, nullptr, 1024);
}

// Round 8
// 213.222 us; speedup vs baseline: 1.0949x; 1.0949x over previous
//
#include <hip/hip_runtime.h>
#include <hip/hip_bf16.h>

#define DEVI __device__ __forceinline__

typedef __attribute__((ext_vector_type(8))) _Float16 f16x8;
typedef __attribute__((ext_vector_type(4))) float f32x4;
typedef __attribute__((ext_vector_type(4))) unsigned short us4;

DEVI unsigned short f2h(float f) {
  union { _Float16 h; unsigned short u; } v;
  v.h = (_Float16)f;
  return v.u;
}

// ---------------- elementwise convert x -> fp16 (2 float4 / thread) -----------
__global__ void __launch_bounds__(256) k_convert_f16(
    const float* __restrict__ x, unsigned short* __restrict__ o, int n4) {
  int base = blockIdx.x * 512 + threadIdx.x;
#pragma unroll
  for (int h = 0; h < 2; ++h) {
    int i = base + h * 256;
    if (i < n4) {
      float4 v = reinterpret_cast<const float4*>(x)[i];
      us4 u;
      u[0] = f2h(v.x); u[1] = f2h(v.y); u[2] = f2h(v.z); u[3] = f2h(v.w);
      reinterpret_cast<us4*>(o)[i] = u;
    }
  }
}

// ------------- merged transpose: 4 weights [K][N] -> WT[N][K] fp16 -------------
__global__ void __launch_bounds__(256) k_transpose4(
    const float* __restrict__ W0, const float* __restrict__ W1,
    const float* __restrict__ W2, const float* __restrict__ W3,
    unsigned short* __restrict__ T0, unsigned short* __restrict__ T1,
    unsigned short* __restrict__ T2, unsigned short* __restrict__ T3, int n) {
  const int zz = blockIdx.z;
  const float* W = (zz == 0) ? W0 : (zz == 1) ? W1 : (zz == 2) ? W2 : W3;
  unsigned short* T = (zz == 0) ? T0 : (zz == 1) ? T1 : (zz == 2) ? T2 : T3;
  __shared__ float t[32][33];
  int tx = threadIdx.x & 31, ty = threadIdx.x >> 5;
  int n0 = blockIdx.x * 32, k0 = blockIdx.y * 32;
#pragma unroll
  for (int r = 0; r < 4; ++r)
    t[ty + r * 8][tx] = W[(size_t)(k0 + ty + r * 8) * n + n0 + tx];
  __syncthreads();
#pragma unroll
  for (int r = 0; r < 4; ++r) {
    int nn = n0 + ty + r * 8;
    T[(size_t)nn * n + k0 + tx] = f2h(t[tx][ty + r * 8]);
  }
}

// -------- v transpose: v_r [8192 s][1024 d] -> v_t [4][1024 d][2048 s] --------
// 64x64 tiles through LDS (pad 72); both global sides coalesced.
__global__ void __launch_bounds__(256) k_vtrans(
    const unsigned short* __restrict__ vr, unsigned short* __restrict__ vt) {
  __shared__ unsigned short t[64 * 72];
  const int tid = threadIdx.x;
  const int s0 = blockIdx.x * 64;   // global s base (tile fully inside a batch)
  const int d0 = blockIdx.y * 64;
  {
    const int s = tid >> 2;          // 0..63
    const int dq = (tid & 3) * 16;   // 0,16,32,48
#pragma unroll
    for (int c = 0; c < 4; ++c) {
      us4 v = *reinterpret_cast<const us4*>(vr + (size_t)(s0 + s) * 1024 + d0 + dq + c * 4);
#pragma unroll
      for (int e = 0; e < 4; ++e) t[(dq + c * 4 + e) * 72 + s] = v[e];
    }
  }
  __syncthreads();
  const int lane = tid & 63, wid = tid >> 6;
  const size_t bofs = (size_t)(s0 >> 11) * 1024 * 2048;
  const int sloc = (s0 & 2047) + (lane & 15) * 4;
#pragma unroll
  for (int i = 0; i < 4; ++i) {
    const int d = i * 16 + wid * 4 + (lane >> 4);  // local d 0..63
    us4 o;
#pragma unroll
    for (int j = 0; j < 4; ++j) o[j] = t[d * 72 + (lane & 15) * 4 + j];
    *reinterpret_cast<us4*>(vt + bofs + (size_t)(d0 + d) * 2048 + sloc) = o;
  }
}

// ---------------- GEMM: C[M][N] = A[M][K] * B_T[N][K]  (fp16, K-contiguous)
// 128x128 tile, BK=64, 256 thr, 4 blocks/CU (proven config).
// XOR-swizzled LDS staged via inverse-swizzled global source (global_load_lds).
DEVI void gload16(const unsigned short* gp, unsigned short* lp) {
  __builtin_amdgcn_global_load_lds(
      (const __attribute__((address_space(1))) unsigned int*)gp,
      (__attribute__((address_space(3))) unsigned int*)lp, 16, 0, 0);
}

DEVI void stage_tile64(unsigned short* lbase, const unsigned short* g, int ldg,
                       int wid, int lane) {
#pragma unroll
  for (int it = 0; it < 4; ++it) {
    int chunk = it * 256 + wid * 64 + lane;
    int r = chunk >> 3, s = chunk & 7;
    int c = (s ^ (r & 7)) * 8;
    gload16(g + (size_t)r * ldg + c, lbase + (it * 256 + wid * 64) * 8);
  }
}

DEVI f16x8 frag(const unsigned short* base, int row, int kk, int lr) {
  int slot = (kk * 4 + lr) ^ (row & 7);
  return *reinterpret_cast<const f16x8*>(base + row * 64 + slot * 8);
}

// EPI: 0 = fused QKV: bias + fp16 row-major q/k/v_r
//      2 = write fp32 (scores, z-strided)
//      3 = write fp16 (attn = P*V, z-strided)
//      4 = bias + residual + write fp32 (out proj)
// XY: 0 = gridDim.x indexes M-tiles; 1 = gridDim.x indexes N-tiles (per-XCD
//     chunks then hold a resident A row-panel — better L2 locality).
template <int EPI, int XY>
__global__ void __launch_bounds__(256, 4) k_gemm(
    const unsigned short* __restrict__ A, const unsigned short* __restrict__ B,
    int K, int ldA, int ldB,
    size_t azs, size_t bzs, size_t czs,
    const float* __restrict__ b0, const float* __restrict__ b1,
    const float* __restrict__ b2, const float* __restrict__ resid,
    float* __restrict__ outF, unsigned short* __restrict__ o0,
    unsigned short* __restrict__ o1, unsigned short* __restrict__ o2, int ldc) {
  __shared__ unsigned short lds[2 * 8192];
  unsigned short* Alds = lds;
  unsigned short* Blds = lds + 8192;

  // bijective chunked XCD swizzle (all launch grids have nwg % 8 == 0)
  const int gx = gridDim.x, gy = gridDim.y;
  const int nwg = gx * gy * gridDim.z;
  const int l = (blockIdx.z * gy + blockIdx.y) * gx + blockIdx.x;
  const int nl = (l & 7) * (nwg >> 3) + (l >> 3);
  const int bx = nl % gx;
  const int rem = nl / gx;
  const int by = rem % gy;
  const int z = rem / gy;
  const int rb = XY ? by : bx;   // row-tile index
  const int cb = XY ? bx : by;   // col-tile index

  const int tid = threadIdx.x, lane = tid & 63, wid = tid >> 6;
  const int wr = (wid >> 1) * 64, wc = (wid & 1) * 64;
  const int lc = lane & 15, lr = lane >> 4;
  const size_t row0 = (size_t)rb * 128, col0 = (size_t)cb * 128;

  const unsigned short* Ag = A + (size_t)z * azs + row0 * ldA;
  const unsigned short* Bg = B + (size_t)z * bzs + col0 * ldB;

  f32x4 acc[4][4] = {};

  for (int k0 = 0; k0 < K; k0 += 64) {
    stage_tile64(Alds, Ag + k0, ldA, wid, lane);
    stage_tile64(Blds, Bg + k0, ldB, wid, lane);
    __syncthreads();
#pragma unroll
    for (int kk = 0; kk < 2; ++kk) {
      f16x8 af[4], bf[4];
#pragma unroll
      for (int i = 0; i < 4; ++i) {
        af[i] = frag(Alds, wr + i * 16 + lc, kk, lr);
        bf[i] = frag(Blds, wc + i * 16 + lc, kk, lr);
      }
#pragma unroll
      for (int mi = 0; mi < 4; ++mi)
#pragma unroll
        for (int ni = 0; ni < 4; ++ni)
          acc[mi][ni] = __builtin_amdgcn_mfma_f32_16x16x32_f16(af[mi], bf[ni], acc[mi][ni], 0, 0, 0);
    }
    __syncthreads();
  }

#pragma unroll
  for (int mi = 0; mi < 4; ++mi) {
#pragma unroll
    for (int ni = 0; ni < 4; ++ni) {
      const int r0 = (int)row0 + wr + mi * 16 + lr * 4;
      const int c = (int)col0 + wc + ni * 16 + lc;
      f32x4 a = acc[mi][ni];
      if (EPI == 0) {
        const int sub = c >> 10;  // 128-tile never spans q/k/v boundary
        const int cc = c & 1023;
        unsigned short* dst = (sub == 0) ? o0 : (sub == 1) ? o1 : o2;
        const float bb = ((sub == 0) ? b0 : (sub == 1) ? b1 : b2)[cc];
#pragma unroll
        for (int r = 0; r < 4; ++r)
          dst[(size_t)(r0 + r) * 1024 + cc] = f2h(a[r] + bb);
      } else if (EPI == 2) {
#pragma unroll
        for (int r = 0; r < 4; ++r)
          outF[(size_t)z * czs + (size_t)(r0 + r) * ldc + c] = a[r];
      } else if (EPI == 3) {
#pragma unroll
        for (int r = 0; r < 4; ++r)
          o0[(size_t)z * czs + (size_t)(r0 + r) * ldc + c] = f2h(a[r]);
      } else {
        float bb = b0[c];
#pragma unroll
        for (int r = 0; r < 4; ++r) {
          size_t idx = (size_t)(r0 + r) * ldc + c;
          outF[idx] = a[r] + bb + resid[idx];
        }
      }
    }
  }
}

// ---------------- row softmax: scores fp32 [8192][2048] -> P fp16 [8192][2048]
__global__ void __launch_bounds__(256) k_softmax(
    const float* __restrict__ S, unsigned short* __restrict__ P) {
  __shared__ float red[4];
  const int row = blockIdx.x, tid = threadIdx.x;
  const int lane = tid & 63, wid = tid >> 6;
  const float* src = S + (size_t)row * 2048;
  float4 v0 = *reinterpret_cast<const float4*>(src + tid * 8);
  float4 v1 = *reinterpret_cast<const float4*>(src + tid * 8 + 4);
  float vv[8] = {v0.x, v0.y, v0.z, v0.w, v1.x, v1.y, v1.z, v1.w};
  float m = vv[0];
#pragma unroll
  for (int j = 1; j < 8; ++j) m = fmaxf(m, vv[j]);
#pragma unroll
  for (int o = 32; o > 0; o >>= 1) m = fmaxf(m, __shfl_xor(m, o));
  if (lane == 0) red[wid] = m;
  __syncthreads();
  m = fmaxf(fmaxf(red[0], red[1]), fmaxf(red[2], red[3]));
  __syncthreads();
  float e[8];
  float s = 0.f;
#pragma unroll
  for (int j = 0; j < 8; ++j) { e[j] = __expf(vv[j] - m); s += e[j]; }
#pragma unroll
  for (int o = 32; o > 0; o >>= 1) s += __shfl_xor(s, o);
  if (lane == 0) red[wid] = s;
  __syncthreads();
  s = red[0] + red[1] + red[2] + red[3];
  float inv = 1.0f / s;
  us4 p0, p1;
#pragma unroll
  for (int j = 0; j < 4; ++j) p0[j] = f2h(e[j] * inv);
#pragma unroll
  for (int j = 0; j < 4; ++j) p1[j] = f2h(e[j + 4] * inv);
  us4* dst = reinterpret_cast<us4*>(P + (size_t)row * 2048 + tid * 8);
  dst[0] = p0;
  dst[1] = p1;
}

extern "C" void kernel_launch(void* const* d_in, const int* in_sizes, int n_in,
                              void* d_out, int out_size, void* d_ws, size_t ws_size,
                              hipStream_t stream) {
  (void)in_sizes; (void)n_in; (void)out_size; (void)ws_size;
  const float* x  = (const float*)d_in[0];
  const float* Wq = (const float*)d_in[1];
  const float* bq = (const float*)d_in[2];
  const float* Wk = (const float*)d_in[3];
  const float* bk = (const float*)d_in[4];
  const float* Wv = (const float*)d_in[5];
  const float* bv = (const float*)d_in[6];
  const float* Wo = (const float*)d_in[7];
  const float* bo = (const float*)d_in[8];
  float* out = (float*)d_out;

  char* p = (char*)d_ws;
  auto take = [&](size_t bytes) {
    char* r = p;
    p += (bytes + 255) & ~(size_t)255;
    return r;
  };
  const size_t SD = (size_t)4 * 2048 * 1024;  // 8388608 elements
  unsigned short* x_h   = (unsigned short*)take(SD * 2);
  unsigned short* q_h   = (unsigned short*)take(SD * 2);
  unsigned short* k_h   = (unsigned short*)take(SD * 2);
  unsigned short* v_r   = (unsigned short*)take(SD * 2);   // [B*S][D] fp16
  unsigned short* WqkvT = (unsigned short*)take((size_t)3072 * 1024 * 2);
  unsigned short* WoT   = (unsigned short*)take((size_t)1024 * 1024 * 2);
  unsigned short* v_t   = (unsigned short*)take(SD * 2);   // [B][D][S] fp16
  unsigned short* attn  = (unsigned short*)take(SD * 2);   // [B*S][D] fp16
  const size_t SC_B = (size_t)2048 * 2048;  // score elements per batch
  float* scores       = (float*)take(4 * SC_B * 4);          // fp32 [4][2048][2048]
  unsigned short* Pm  = (unsigned short*)take(4 * SC_B * 2); // fp16 [4][2048][2048]

  dim3 blk(256);
  k_convert_f16<<<dim3(4096), blk, 0, stream>>>(x, x_h, (int)(SD / 4));
  k_transpose4<<<dim3(32, 32, 4), blk, 0, stream>>>(
      Wq, Wk, Wv, Wo,
      WqkvT, WqkvT + (size_t)1024 * 1024, WqkvT + (size_t)2048 * 1024, WoT, 1024);

  // fused QKV projection: [8192 x 1024] x [3072 x 1024]^T (XY=1: x = N-tiles)
  k_gemm<0, 1><<<dim3(24, 64, 1), blk, 0, stream>>>(
      x_h, WqkvT, 1024, 1024, 1024, 0, 0, 0,
      bq, bk, bv, nullptr, nullptr, q_h, k_h, v_r, 0);

  // v_r -> v_t transpose (coalesced both sides)
  k_vtrans<<<dim3(128, 16), blk, 0, stream>>>(v_r, v_t);

  const size_t QZS = (size_t)2048 * 1024;   // q/k batch stride (elements)
  const size_t VZS = (size_t)1024 * 2048;   // v_t batch stride
  // scores = q . k^T  (fp32 out), all 4 batches
  k_gemm<2, 0><<<dim3(16, 16, 4), blk, 0, stream>>>(
      q_h, k_h, 1024, 1024, 1024, QZS, QZS, SC_B,
      nullptr, nullptr, nullptr, nullptr, scores, nullptr, nullptr, nullptr, 2048);
  // softmax: fp32 scores -> contiguous fp16 P
  k_softmax<<<dim3(8192), blk, 0, stream>>>(scores, Pm);
  // attn = P . V
  k_gemm<3, 0><<<dim3(16, 8, 4), blk, 0, stream>>>(
      Pm, v_t, 2048, 2048, 2048, SC_B, VZS, QZS,
      nullptr, nullptr, nullptr, nullptr, nullptr, attn, nullptr, nullptr, 1024);
  // out = attn . Wo^T + bo + x  (XY=1)
  k_gemm<4, 1><<<dim3(8, 64, 1), blk, 0, stream>>>(
      attn, WoT, 1024, 1024, 1024, 0, 0, 0,
      bo, nullptr, nullptr, x, out, nullptr, nullptr, nullptr, 1024);
}

// Round 9
// 198.763 us; speedup vs baseline: 1.1746x; 1.0727x over previous
//
#include <hip/hip_runtime.h>
#include <hip/hip_bf16.h>

#define DEVI __device__ __forceinline__

typedef __attribute__((ext_vector_type(8))) _Float16 f16x8;
typedef __attribute__((ext_vector_type(4))) float f32x4;
typedef __attribute__((ext_vector_type(4))) unsigned short us4;

DEVI unsigned short f2h(float f) {
  union { _Float16 h; unsigned short u; } v;
  v.h = (_Float16)f;
  return v.u;
}

// ------- merged prep: x -> fp16 (blocks 0..4095) + 4 weight transposes -------
__global__ void __launch_bounds__(256) k_prep(
    const float* __restrict__ x, unsigned short* __restrict__ xh,
    const float* __restrict__ W0, const float* __restrict__ W1,
    const float* __restrict__ W2, const float* __restrict__ W3,
    unsigned short* __restrict__ T0, unsigned short* __restrict__ T1,
    unsigned short* __restrict__ T2, unsigned short* __restrict__ T3) {
  __shared__ float t[32][33];
  const int b = blockIdx.x;
  if (b < 4096) {
    int base = b * 512 + threadIdx.x;
#pragma unroll
    for (int h = 0; h < 2; ++h) {
      int i = base + h * 256;
      float4 v = reinterpret_cast<const float4*>(x)[i];
      us4 u;
      u[0] = f2h(v.x); u[1] = f2h(v.y); u[2] = f2h(v.z); u[3] = f2h(v.w);
      reinterpret_cast<us4*>(xh)[i] = u;
    }
    return;
  }
  const int tt = b - 4096;
  const int zz = tt >> 10, r = tt & 1023;
  const int n0 = (r & 31) * 32, k0 = (r >> 5) * 32;
  const float* W = (zz == 0) ? W0 : (zz == 1) ? W1 : (zz == 2) ? W2 : W3;
  unsigned short* T = (zz == 0) ? T0 : (zz == 1) ? T1 : (zz == 2) ? T2 : T3;
  int tx = threadIdx.x & 31, ty = threadIdx.x >> 5;
#pragma unroll
  for (int rr = 0; rr < 4; ++rr)
    t[ty + rr * 8][tx] = W[(size_t)(k0 + ty + rr * 8) * 1024 + n0 + tx];
  __syncthreads();
#pragma unroll
  for (int rr = 0; rr < 4; ++rr) {
    int nn = n0 + ty + rr * 8;
    T[(size_t)nn * 1024 + k0 + tx] = f2h(t[tx][ty + rr * 8]);
  }
}

// ---------------- GEMM: C[M][N] = A[M][K] * B_T[N][K]  (fp16, K-contiguous)
// 128x128 tile, BK=64, 256 thr, 4 blocks/CU (proven ceiling config).
// Block ordering: XCD-chunked linear id over 4x4 supertiles (launch grid
// (16, TR4*TC4, Z); the 16 x-blocks are one supertile -> 2MB A + 2MB B
// working set per supertile, L2-resident per XCD).
DEVI void gload16(const unsigned short* gp, unsigned short* lp) {
  __builtin_amdgcn_global_load_lds(
      (const __attribute__((address_space(1))) unsigned int*)gp,
      (__attribute__((address_space(3))) unsigned int*)lp, 16, 0, 0);
}

DEVI void stage_tile64(unsigned short* lbase, const unsigned short* g, int ldg,
                       int wid, int lane) {
#pragma unroll
  for (int it = 0; it < 4; ++it) {
    int chunk = it * 256 + wid * 64 + lane;
    int r = chunk >> 3, s = chunk & 7;
    int c = (s ^ (r & 7)) * 8;
    gload16(g + (size_t)r * ldg + c, lbase + (it * 256 + wid * 64) * 8);
  }
}

DEVI f16x8 frag(const unsigned short* base, int row, int kk, int lr) {
  int slot = (kk * 4 + lr) ^ (row & 7);
  return *reinterpret_cast<const f16x8*>(base + row * 64 + slot * 8);
}

// EPI: 0 = fused QKV: bias; q,k fp16 row-major; v transposed to v_t via LDS
//      2 = write fp32 (scores, z-strided)
//      3 = write fp16 (attn = P*V, z-strided)
//      4 = bias + residual + write fp32 (out proj)
template <int EPI>
__global__ void __launch_bounds__(256, 4) k_gemm(
    const unsigned short* __restrict__ A, const unsigned short* __restrict__ B,
    int K, int ldA, int ldB, int TC4,
    size_t azs, size_t bzs, size_t czs,
    const float* __restrict__ b0, const float* __restrict__ b1,
    const float* __restrict__ b2, const float* __restrict__ resid,
    float* __restrict__ outF, unsigned short* __restrict__ o0,
    unsigned short* __restrict__ o1, unsigned short* __restrict__ o2, int ldc) {
  __shared__ unsigned short lds[2 * 8192];
  unsigned short* Alds = lds;
  unsigned short* Blds = lds + 8192;

  // XCD-chunked supertile decode
  const int nwg = 16 * gridDim.y * gridDim.z;
  const int l = (blockIdx.z * gridDim.y + blockIdx.y) * 16 + blockIdx.x;
  const int nl = (l & 7) * (nwg >> 3) + (l >> 3);
  const int pos = nl & 15;
  const int st = nl >> 4;
  const int TR4 = gridDim.y / TC4;
  const int stc = st % TC4;
  const int st2 = st / TC4;
  const int str = st2 % TR4;
  const int z = st2 / TR4;
  const int rb = str * 4 + (pos >> 2);
  const int cb = stc * 4 + (pos & 3);

  const int tid = threadIdx.x, lane = tid & 63, wid = tid >> 6;
  const int wr = (wid >> 1) * 64, wc = (wid & 1) * 64;
  const int lc = lane & 15, lr = lane >> 4;
  const size_t row0 = (size_t)rb * 128, col0 = (size_t)cb * 128;

  const unsigned short* Ag = A + (size_t)z * azs + row0 * ldA;
  const unsigned short* Bg = B + (size_t)z * bzs + col0 * ldB;

  f32x4 acc[4][4] = {};

  for (int k0 = 0; k0 < K; k0 += 64) {
    stage_tile64(Alds, Ag + k0, ldA, wid, lane);
    stage_tile64(Blds, Bg + k0, ldB, wid, lane);
    __syncthreads();
#pragma unroll
    for (int kk = 0; kk < 2; ++kk) {
      f16x8 af[4], bf[4];
#pragma unroll
      for (int i = 0; i < 4; ++i) {
        af[i] = frag(Alds, wr + i * 16 + lc, kk, lr);
        bf[i] = frag(Blds, wc + i * 16 + lc, kk, lr);
      }
#pragma unroll
      for (int mi = 0; mi < 4; ++mi)
#pragma unroll
        for (int ni = 0; ni < 4; ++ni)
          acc[mi][ni] = __builtin_amdgcn_mfma_f32_16x16x32_f16(af[mi], bf[ni], acc[mi][ni], 0, 0, 0);
    }
    __syncthreads();
  }

  if (EPI == 0 && cb >= 16) {
    // v-tile: transpose 128 s x 128 d through LDS (two 64-s halves), store
    // s-contiguous lines to v_t[b][d][s]. LDS reused post-K-loop; 68-pad rows.
    const int dbase = (int)col0 - 2048;
    unsigned short* vt = lds;  // 128 x 68 fp16 = 17408 B
#pragma unroll
    for (int h = 0; h < 2; ++h) {
      __syncthreads();
      if ((wid >> 1) == h) {
#pragma unroll
        for (int mi = 0; mi < 4; ++mi)
#pragma unroll
          for (int ni = 0; ni < 4; ++ni) {
            const int sloc = mi * 16 + lr * 4;
            const int dloc = wc + ni * 16 + lc;
            const float bb = b2[dbase + dloc];
#pragma unroll
            for (int r = 0; r < 4; ++r)
              vt[dloc * 68 + sloc + r] = f2h(acc[mi][ni][r] + bb);
          }
      }
      __syncthreads();
      {
        const int d = tid >> 1, sc = (tid & 1) * 32;
        const unsigned short* src = vt + d * 68 + sc;
        unsigned short* dst = o2 + ((size_t)(row0 >> 11) * 1024 + (dbase + d)) * 2048 +
                              ((int)(row0 & 2047) + h * 64 + sc);
#pragma unroll
        for (int j = 0; j < 8; ++j)
          reinterpret_cast<us4*>(dst)[j] = *reinterpret_cast<const us4*>(src + j * 4);
      }
    }
    return;
  }

#pragma unroll
  for (int mi = 0; mi < 4; ++mi) {
#pragma unroll
    for (int ni = 0; ni < 4; ++ni) {
      const int r0 = (int)row0 + wr + mi * 16 + lr * 4;
      const int c = (int)col0 + wc + ni * 16 + lc;
      f32x4 a = acc[mi][ni];
      if (EPI == 0) {
        const int sub = cb >> 3;  // 0 = q, 1 = k (v handled above)
        const int cc = c & 1023;
        unsigned short* dst = (sub == 0) ? o0 : o1;
        const float bb = ((sub == 0) ? b0 : b1)[cc];
#pragma unroll
        for (int r = 0; r < 4; ++r)
          dst[(size_t)(r0 + r) * 1024 + cc] = f2h(a[r] + bb);
      } else if (EPI == 2) {
#pragma unroll
        for (int r = 0; r < 4; ++r)
          outF[(size_t)z * czs + (size_t)(r0 + r) * ldc + c] = a[r];
      } else if (EPI == 3) {
#pragma unroll
        for (int r = 0; r < 4; ++r)
          o0[(size_t)z * czs + (size_t)(r0 + r) * ldc + c] = f2h(a[r]);
      } else {
        float bb = b0[c];
#pragma unroll
        for (int r = 0; r < 4; ++r) {
          size_t idx = (size_t)(r0 + r) * ldc + c;
          outF[idx] = a[r] + bb + resid[idx];
        }
      }
    }
  }
}

// ---------------- row softmax: scores fp32 [8192][2048] -> P fp16 [8192][2048]
__global__ void __launch_bounds__(256) k_softmax(
    const float* __restrict__ S, unsigned short* __restrict__ P) {
  __shared__ float red[4];
  const int row = blockIdx.x, tid = threadIdx.x;
  const int lane = tid & 63, wid = tid >> 6;
  const float* src = S + (size_t)row * 2048;
  float4 v0 = *reinterpret_cast<const float4*>(src + tid * 8);
  float4 v1 = *reinterpret_cast<const float4*>(src + tid * 8 + 4);
  float vv[8] = {v0.x, v0.y, v0.z, v0.w, v1.x, v1.y, v1.z, v1.w};
  float m = vv[0];
#pragma unroll
  for (int j = 1; j < 8; ++j) m = fmaxf(m, vv[j]);
#pragma unroll
  for (int o = 32; o > 0; o >>= 1) m = fmaxf(m, __shfl_xor(m, o));
  if (lane == 0) red[wid] = m;
  __syncthreads();
  m = fmaxf(fmaxf(red[0], red[1]), fmaxf(red[2], red[3]));
  __syncthreads();
  float e[8];
  float s = 0.f;
#pragma unroll
  for (int j = 0; j < 8; ++j) { e[j] = __expf(vv[j] - m); s += e[j]; }
#pragma unroll
  for (int o = 32; o > 0; o >>= 1) s += __shfl_xor(s, o);
  if (lane == 0) red[wid] = s;
  __syncthreads();
  s = red[0] + red[1] + red[2] + red[3];
  float inv = 1.0f / s;
  us4 p0, p1;
#pragma unroll
  for (int j = 0; j < 4; ++j) p0[j] = f2h(e[j] * inv);
#pragma unroll
  for (int j = 0; j < 4; ++j) p1[j] = f2h(e[j + 4] * inv);
  us4* dst = reinterpret_cast<us4*>(P + (size_t)row * 2048 + tid * 8);
  dst[0] = p0;
  dst[1] = p1;
}

extern "C" void kernel_launch(void* const* d_in, const int* in_sizes, int n_in,
                              void* d_out, int out_size, void* d_ws, size_t ws_size,
                              hipStream_t stream) {
  (void)in_sizes; (void)n_in; (void)out_size; (void)ws_size;
  const float* x  = (const float*)d_in[0];
  const float* Wq = (const float*)d_in[1];
  const float* bq = (const float*)d_in[2];
  const float* Wk = (const float*)d_in[3];
  const float* bk = (const float*)d_in[4];
  const float* Wv = (const float*)d_in[5];
  const float* bv = (const float*)d_in[6];
  const float* Wo = (const float*)d_in[7];
  const float* bo = (const float*)d_in[8];
  float* out = (float*)d_out;

  char* p = (char*)d_ws;
  auto take = [&](size_t bytes) {
    char* r = p;
    p += (bytes + 255) & ~(size_t)255;
    return r;
  };
  const size_t SD = (size_t)4 * 2048 * 1024;  // 8388608 elements
  unsigned short* x_h   = (unsigned short*)take(SD * 2);
  unsigned short* q_h   = (unsigned short*)take(SD * 2);
  unsigned short* k_h   = (unsigned short*)take(SD * 2);
  unsigned short* WqkvT = (unsigned short*)take((size_t)3072 * 1024 * 2);
  unsigned short* WoT   = (unsigned short*)take((size_t)1024 * 1024 * 2);
  unsigned short* v_t   = (unsigned short*)take(SD * 2);   // [B][D][S] fp16
  unsigned short* attn  = (unsigned short*)take(SD * 2);   // [B*S][D] fp16
  const size_t SC_B = (size_t)2048 * 2048;  // score elements per batch
  float* scores       = (float*)take(4 * SC_B * 4);          // fp32 [4][2048][2048]
  unsigned short* Pm  = (unsigned short*)take(4 * SC_B * 2); // fp16 [4][2048][2048]

  dim3 blk(256);
  // prep: convert x (blocks 0..4095) + transpose 4 weights (blocks 4096..8191)
  k_prep<<<dim3(8192), blk, 0, stream>>>(
      x, x_h, Wq, Wk, Wv, Wo,
      WqkvT, WqkvT + (size_t)1024 * 1024, WqkvT + (size_t)2048 * 1024, WoT);

  // fused QKV projection: [8192 x 1024] x [3072 x 1024]^T; TR=64,TC=24
  k_gemm<0><<<dim3(16, 96, 1), blk, 0, stream>>>(
      x_h, WqkvT, 1024, 1024, 1024, 6, 0, 0, 0,
      bq, bk, bv, nullptr, nullptr, q_h, k_h, v_t, 0);

  const size_t QZS = (size_t)2048 * 1024;   // q/k batch stride (elements)
  const size_t VZS = (size_t)1024 * 2048;   // v_t batch stride
  // scores = q . k^T  (fp32 out), 4 batches; TR=TC=16
  k_gemm<2><<<dim3(16, 16, 4), blk, 0, stream>>>(
      q_h, k_h, 1024, 1024, 1024, 4, QZS, QZS, SC_B,
      nullptr, nullptr, nullptr, nullptr, scores, nullptr, nullptr, nullptr, 2048);
  // softmax: fp32 scores -> contiguous fp16 P
  k_softmax<<<dim3(8192), blk, 0, stream>>>(scores, Pm);
  // attn = P . V; TR=16, TC=8
  k_gemm<3><<<dim3(16, 8, 4), blk, 0, stream>>>(
      Pm, v_t, 2048, 2048, 2048, 2, SC_B, VZS, QZS,
      nullptr, nullptr, nullptr, nullptr, nullptr, attn, nullptr, nullptr, 1024);
  // out = attn . Wo^T + bo + x; TR=64, TC=8
  k_gemm<4><<<dim3(16, 32, 1), blk, 0, stream>>>(
      attn, WoT, 1024, 1024, 1024, 2, 0, 0, 0,
      bo, nullptr, nullptr, x, out, nullptr, nullptr, nullptr, 1024);
}